// Round 1
// baseline (999.719 us; speedup 1.0000x reference)
//
#include <hip/hip_runtime.h>

// ---- problem constants (match reference) ----
#define NTOK   16384      // B*T
#define DMODEL 1024
#define FFF    4096
#define NEXP   8
#define CAP    2560       // int(1.25 * NTOK / NEXP)
#define NASSIGN (NTOK*2)  // top-2

typedef __bf16 bf16x8 __attribute__((ext_vector_type(8)));
typedef float  f32x4  __attribute__((ext_vector_type(4)));

__device__ __forceinline__ unsigned short f2bf(float f) {
    unsigned int u = __float_as_uint(f);
    u = u + 0x7FFFu + ((u >> 16) & 1u);   // RNE
    return (unsigned short)(u >> 16);
}
__device__ __forceinline__ float bf2f(unsigned short s) {
    return __uint_as_float(((unsigned int)s) << 16);
}

// ---------------- router: logits -> softmax -> top2 ----------------
__global__ void router_kernel(const float* __restrict__ x,
                              const float* __restrict__ wr,
                              const float* __restrict__ br,
                              int* __restrict__ topi,
                              float* __restrict__ topv) {
    int t    = blockIdx.x * 4 + (threadIdx.x >> 6);
    int lane = threadIdx.x & 63;
    const float* xr = x + (size_t)t * DMODEL;
    float a[8] = {0.f,0.f,0.f,0.f,0.f,0.f,0.f,0.f};
    for (int d = lane; d < DMODEL; d += 64) {
        float xv = xr[d];
        const float* w = wr + d * 8;
        #pragma unroll
        for (int e = 0; e < 8; e++) a[e] = fmaf(xv, w[e], a[e]);
    }
    #pragma unroll
    for (int off = 32; off > 0; off >>= 1) {
        #pragma unroll
        for (int e = 0; e < 8; e++) a[e] += __shfl_xor(a[e], off, 64);
    }
    if (lane == 0) {
        float l[8], g[8];
        float mx = -1e30f;
        #pragma unroll
        for (int e = 0; e < 8; e++) { l[e] = a[e] + br[e]; mx = fmaxf(mx, l[e]); }
        float s = 0.f;
        #pragma unroll
        for (int e = 0; e < 8; e++) { g[e] = expf(l[e] - mx); s += g[e]; }
        float inv = 1.f / s;
        #pragma unroll
        for (int e = 0; e < 8; e++) g[e] *= inv;
        // top-2, lowest index wins ties (jax.lax.top_k semantics)
        float v1 = -1.f, v2 = -1.f; int i1 = 0, i2 = 0;
        #pragma unroll
        for (int e = 0; e < 8; e++) {
            float v = g[e];
            if (v > v1)      { v2 = v1; i2 = i1; v1 = v; i1 = e; }
            else if (v > v2) { v2 = v; i2 = e; }
        }
        topi[t*2]   = i1; topi[t*2+1] = i2;
        topv[t*2]   = v1; topv[t*2+1] = v2;
    }
}

// ------- scan: arrival-order positions per expert (single block) -------
__global__ void scan_kernel(const int* __restrict__ topi,
                            int* __restrict__ pos,
                            int* __restrict__ slot_tok,
                            int* __restrict__ kept) {
    const int APT = NASSIGN / 256;  // 128 assignments per thread, in order
    int tid = threadIdx.x, lane = tid & 63, w = tid >> 6;
    int base = tid * APT;
    int c[8] = {0,0,0,0,0,0,0,0};
    for (int i = 0; i < APT; i++) {
        int e = topi[base + i];
        #pragma unroll
        for (int q = 0; q < 8; q++) c[q] += (e == q);
    }
    int excl[8], wtot[8];
    #pragma unroll
    for (int e = 0; e < 8; e++) {
        int s = c[e];
        for (int off = 1; off < 64; off <<= 1) {
            int n = __shfl_up(s, off, 64);
            if (lane >= off) s += n;
        }
        excl[e] = s - c[e];
        wtot[e] = __shfl(s, 63, 64);
    }
    __shared__ int woff[4][8];
    if (lane == 0) {
        #pragma unroll
        for (int e = 0; e < 8; e++) woff[w][e] = wtot[e];
    }
    __syncthreads();
    if (tid == 0) {
        for (int e = 0; e < 8; e++) {
            int run = 0;
            for (int ww = 0; ww < 4; ww++) { int t0 = woff[ww][e]; woff[ww][e] = run; run += t0; }
            kept[e] = run < CAP ? run : CAP;
        }
    }
    __syncthreads();
    int run[8];
    #pragma unroll
    for (int e = 0; e < 8; e++) run[e] = woff[w][e] + excl[e];
    for (int i = 0; i < APT; i++) {
        int a = base + i;
        int e = topi[a];
        int p = 0;
        #pragma unroll
        for (int q = 0; q < 8; q++) if (e == q) { p = run[q]; run[q] = p + 1; }
        pos[a] = p;
        if (p < CAP) slot_tok[(size_t)e * CAP + p] = a >> 1;
    }
}

// ------------- dispatch: gather kept tokens -> bf16 [E][CAP][D] -------------
__global__ void dispatch_kernel(const float* __restrict__ x,
                                const int* __restrict__ slot_tok,
                                const int* __restrict__ kept,
                                unsigned short* __restrict__ xb) {
    int row  = blockIdx.x * 4 + (threadIdx.x >> 6);
    int lane = threadIdx.x & 63;
    int e = row / CAP;
    int p = row - e * CAP;
    if (p >= kept[e]) return;           // wave-uniform
    int t = slot_tok[row];
    const float4* src = reinterpret_cast<const float4*>(x + (size_t)t * DMODEL);
    ushort4* dst = reinterpret_cast<ushort4*>(xb + (size_t)row * DMODEL);
    #pragma unroll
    for (int i = lane; i < DMODEL/4; i += 64) {
        float4 v = src[i];
        ushort4 o;
        o.x = f2bf(v.x); o.y = f2bf(v.y); o.z = f2bf(v.z); o.w = f2bf(v.w);
        dst[i] = o;
    }
}

// ------------- transpose fp32 [e][R][C] -> bf16 [e][C][R] -------------
__global__ void transpose_f32_to_bf16(const float* __restrict__ in,
                                      unsigned short* __restrict__ out,
                                      int R, int C) {
    __shared__ float tile[32][33];
    int e = blockIdx.z;
    const float* src = in + (size_t)e * R * C;
    unsigned short* dst = out + (size_t)e * R * C;
    int c0 = blockIdx.x * 32, r0 = blockIdx.y * 32;
    #pragma unroll
    for (int i = threadIdx.y; i < 32; i += 8)
        tile[i][threadIdx.x] = src[(size_t)(r0 + i) * C + c0 + threadIdx.x];
    __syncthreads();
    #pragma unroll
    for (int i = threadIdx.y; i < 32; i += 8)
        dst[(size_t)(c0 + i) * R + r0 + threadIdx.x] = f2bf(tile[threadIdx.x][i]);
}

// ------------- GEMM: C[e][M][N] = A[e][M][K] * Bt[e][N][K]^T + bias -------------
// A,Bt bf16 k-contiguous; C bf16; optional exact GELU.
template<int GELU>
__global__ __launch_bounds__(256, 2)
void gemm_bt(const unsigned short* __restrict__ A,
             const unsigned short* __restrict__ Bt,
             const float* __restrict__ bias,
             unsigned short* __restrict__ C,
             int M, int N, int K) {
    constexpr int BM = 128, BN = 128, BK = 64, LDK = 72; // +8 shorts pad: 2-way banks = free
    __shared__ unsigned short As[BM * LDK];
    __shared__ unsigned short Bs[BN * LDK];
    const int e = blockIdx.z;
    const unsigned short* Ab = A  + (size_t)e * M * K + (size_t)blockIdx.y * BM * K;
    const unsigned short* Bb = Bt + (size_t)e * N * K + (size_t)blockIdx.x * BN * K;
    const float* bp = bias + (size_t)e * N;
    const int tid  = threadIdx.x;
    const int lane = tid & 63;
    const int wv   = tid >> 6;
    const int wm   = (wv >> 1) * 64;
    const int wn   = (wv & 1) * 64;
    const int lr   = lane & 15;
    const int quad = lane >> 4;
    const int sr   = tid >> 3;         // staging row 0..31
    const int sc   = (tid & 7) * 8;    // staging col (shorts)

    f32x4 acc[4][4] = {};

    for (int kb = 0; kb < K; kb += BK) {
        #pragma unroll
        for (int s = 0; s < 4; s++) {
            int rr = sr + s * 32;
            *reinterpret_cast<uint4*>(&As[rr * LDK + sc]) =
                *reinterpret_cast<const uint4*>(Ab + (size_t)rr * K + kb + sc);
            *reinterpret_cast<uint4*>(&Bs[rr * LDK + sc]) =
                *reinterpret_cast<const uint4*>(Bb + (size_t)rr * K + kb + sc);
        }
        __syncthreads();
        #pragma unroll
        for (int kk = 0; kk < BK; kk += 32) {
            bf16x8 af[4], bfr[4];
            #pragma unroll
            for (int i = 0; i < 4; i++)
                af[i] = *reinterpret_cast<const bf16x8*>(&As[(wm + i*16 + lr) * LDK + kk + quad*8]);
            #pragma unroll
            for (int j = 0; j < 4; j++)
                bfr[j] = *reinterpret_cast<const bf16x8*>(&Bs[(wn + j*16 + lr) * LDK + kk + quad*8]);
            #pragma unroll
            for (int i = 0; i < 4; i++)
                #pragma unroll
                for (int j = 0; j < 4; j++)
                    acc[i][j] = __builtin_amdgcn_mfma_f32_16x16x32_bf16(af[i], bfr[j], acc[i][j], 0, 0, 0);
        }
        __syncthreads();
    }

    size_t cbase = (size_t)e * M * N + (size_t)blockIdx.y * BM * N + (size_t)blockIdx.x * BN;
    #pragma unroll
    for (int i = 0; i < 4; i++) {
        #pragma unroll
        for (int r = 0; r < 4; r++) {
            int row = wm + i * 16 + quad * 4 + r;
            #pragma unroll
            for (int j = 0; j < 4; j++) {
                int col = wn + j * 16 + lr;
                float v = acc[i][j][r] + bp[blockIdx.x * BN + col];
                if (GELU) v = 0.5f * v * (1.f + erff(v * 0.70710678118654752440f));
                C[cbase + (size_t)row * N + col] = f2bf(v);
            }
        }
    }
}

// ------------- combine: weighted sum of expert outputs, normalize -------------
__global__ void combine_kernel(const int* __restrict__ topi,
                               const float* __restrict__ topv,
                               const int* __restrict__ pos,
                               const unsigned short* __restrict__ out2,
                               float* __restrict__ y) {
    int t    = blockIdx.x * 4 + (threadIdx.x >> 6);
    int lane = threadIdx.x & 63;
    int e0 = topi[t*2],   e1 = topi[t*2+1];
    float g0 = topv[t*2], g1 = topv[t*2+1];
    int p0 = pos[t*2],    p1 = pos[t*2+1];
    float w0 = (p0 < CAP) ? g0 : 0.f;
    float w1 = (p1 < CAP) ? g1 : 0.f;
    float wsum = w0 + w1;
    float scale = (wsum > 0.f) ? 1.f / fmaxf(wsum, 1e-6f) : 0.f;
    int q0 = p0 < CAP ? p0 : CAP - 1;
    int q1 = p1 < CAP ? p1 : CAP - 1;
    const ushort4* o0 = reinterpret_cast<const ushort4*>(out2 + ((size_t)e0 * CAP + q0) * DMODEL);
    const ushort4* o1 = reinterpret_cast<const ushort4*>(out2 + ((size_t)e1 * CAP + q1) * DMODEL);
    float4* dst = reinterpret_cast<float4*>(y + (size_t)t * DMODEL);
    #pragma unroll
    for (int i = lane; i < DMODEL/4; i += 64) {
        ushort4 a = o0[i], b = o1[i];
        float4 r;
        r.x = (w0 * bf2f(a.x) + w1 * bf2f(b.x)) * scale;
        r.y = (w0 * bf2f(a.y) + w1 * bf2f(b.y)) * scale;
        r.z = (w0 * bf2f(a.z) + w1 * bf2f(b.z)) * scale;
        r.w = (w0 * bf2f(a.w) + w1 * bf2f(b.w)) * scale;
        dst[i] = r;
    }
}

extern "C" void kernel_launch(void* const* d_in, const int* in_sizes, int n_in,
                              void* d_out, int out_size, void* d_ws, size_t ws_size,
                              hipStream_t stream) {
    (void)in_sizes; (void)n_in; (void)out_size; (void)ws_size;
    const float* x        = (const float*)d_in[0];
    const float* w_router = (const float*)d_in[1];
    const float* b_router = (const float*)d_in[2];
    const float* w1       = (const float*)d_in[3];
    const float* b1       = (const float*)d_in[4];
    const float* w2       = (const float*)d_in[5];
    const float* b2       = (const float*)d_in[6];
    float* y = (float*)d_out;

    char* ws = (char*)d_ws;
    size_t off = 0;
    auto alloc = [&](size_t n) { char* p = ws + off; off = (off + n + 255) & ~(size_t)255; return p; };
    int*   topi     = (int*)  alloc((size_t)NASSIGN * 4);
    float* topv     = (float*)alloc((size_t)NASSIGN * 4);
    int*   pos      = (int*)  alloc((size_t)NASSIGN * 4);
    int*   slot_tok = (int*)  alloc((size_t)NEXP * CAP * 4);
    int*   kept     = (int*)  alloc(8 * 4);
    unsigned short* w1t = (unsigned short*)alloc((size_t)NEXP * DMODEL * FFF * 2);
    unsigned short* w2t = (unsigned short*)alloc((size_t)NEXP * DMODEL * FFF * 2);
    unsigned short* xb  = (unsigned short*)alloc((size_t)NEXP * CAP * DMODEL * 2);
    unsigned short* h   = (unsigned short*)alloc((size_t)NEXP * CAP * FFF * 2);
    unsigned short* out2 = w1t;  // alias: w1t is dead after GEMM1

    router_kernel<<<NTOK/4, 256, 0, stream>>>(x, w_router, b_router, topi, topv);
    scan_kernel<<<1, 256, 0, stream>>>(topi, pos, slot_tok, kept);
    dispatch_kernel<<<NEXP*CAP/4, 256, 0, stream>>>(x, slot_tok, kept, xb);
    transpose_f32_to_bf16<<<dim3(FFF/32, DMODEL/32, NEXP), dim3(32, 8), 0, stream>>>(w1, w1t, DMODEL, FFF);
    transpose_f32_to_bf16<<<dim3(DMODEL/32, FFF/32, NEXP), dim3(32, 8), 0, stream>>>(w2, w2t, FFF, DMODEL);
    gemm_bt<1><<<dim3(FFF/128, CAP/128, NEXP), 256, 0, stream>>>(xb, w1t, b1, h, CAP, FFF, DMODEL);
    gemm_bt<0><<<dim3(DMODEL/128, CAP/128, NEXP), 256, 0, stream>>>(h, w2t, b2, out2, CAP, DMODEL, FFF);
    combine_kernel<<<NTOK/4, 256, 0, stream>>>(topi, topv, pos, out2, y);
}

// Round 2
// 914.582 us; speedup vs baseline: 1.0931x; 1.0931x over previous
//
#include <hip/hip_runtime.h>

// ---- problem constants (match reference) ----
#define NTOK   16384      // B*T
#define DMODEL 1024
#define FFF    4096
#define NEXP   8
#define CAP    2560       // int(1.25 * NTOK / NEXP)
#define NASSIGN (NTOK*2)  // top-2

typedef __bf16 bf16x8 __attribute__((ext_vector_type(8)));
typedef float  f32x4  __attribute__((ext_vector_type(4)));
typedef unsigned short u16x8 __attribute__((ext_vector_type(8)));

__device__ __forceinline__ unsigned short f2bf(float f) {
    unsigned int u = __float_as_uint(f);
    u = u + 0x7FFFu + ((u >> 16) & 1u);   // RNE
    return (unsigned short)(u >> 16);
}
__device__ __forceinline__ float bf2f(unsigned short s) {
    return __uint_as_float(((unsigned int)s) << 16);
}

// ---------------- router: logits -> softmax -> top2 ----------------
__global__ void router_kernel(const float* __restrict__ x,
                              const float* __restrict__ wr,
                              const float* __restrict__ br,
                              int* __restrict__ topi,
                              float* __restrict__ topv) {
    int t    = blockIdx.x * 4 + (threadIdx.x >> 6);
    int lane = threadIdx.x & 63;
    const float4* xr4 = reinterpret_cast<const float4*>(x + (size_t)t * DMODEL);
    float a[8] = {0.f,0.f,0.f,0.f,0.f,0.f,0.f,0.f};
    #pragma unroll
    for (int i = lane; i < DMODEL/4; i += 64) {
        float4 xv = xr4[i];
        const float* w = wr + i * 32;        // 4 rows of 8
        #pragma unroll
        for (int e = 0; e < 8; e++) a[e] = fmaf(xv.x, w[e],      a[e]);
        #pragma unroll
        for (int e = 0; e < 8; e++) a[e] = fmaf(xv.y, w[8 + e],  a[e]);
        #pragma unroll
        for (int e = 0; e < 8; e++) a[e] = fmaf(xv.z, w[16 + e], a[e]);
        #pragma unroll
        for (int e = 0; e < 8; e++) a[e] = fmaf(xv.w, w[24 + e], a[e]);
    }
    #pragma unroll
    for (int off = 32; off > 0; off >>= 1) {
        #pragma unroll
        for (int e = 0; e < 8; e++) a[e] += __shfl_xor(a[e], off, 64);
    }
    if (lane == 0) {
        float l[8], g[8];
        float mx = -1e30f;
        #pragma unroll
        for (int e = 0; e < 8; e++) { l[e] = a[e] + br[e]; mx = fmaxf(mx, l[e]); }
        float s = 0.f;
        #pragma unroll
        for (int e = 0; e < 8; e++) { g[e] = expf(l[e] - mx); s += g[e]; }
        float inv = 1.f / s;
        #pragma unroll
        for (int e = 0; e < 8; e++) g[e] *= inv;
        // top-2, lowest index wins ties (jax.lax.top_k semantics)
        float v1 = -1.f, v2 = -1.f; int i1 = 0, i2 = 0;
        #pragma unroll
        for (int e = 0; e < 8; e++) {
            float v = g[e];
            if (v > v1)      { v2 = v1; i2 = i1; v1 = v; i1 = e; }
            else if (v > v2) { v2 = v; i2 = e; }
        }
        topi[t*2]   = i1; topi[t*2+1] = i2;
        topv[t*2]   = v1; topv[t*2+1] = v2;
    }
}

// ------- scan: arrival-order positions per expert (single block) -------
__global__ void scan_kernel(const int* __restrict__ topi,
                            int* __restrict__ pos,
                            int* __restrict__ slot_tok,
                            int* __restrict__ kept) {
    const int APT = NASSIGN / 256;  // 128 assignments per thread, in order
    int tid = threadIdx.x, lane = tid & 63, w = tid >> 6;
    int base = tid * APT;
    const int4* tp = reinterpret_cast<const int4*>(topi + base);
    int c[8] = {0,0,0,0,0,0,0,0};
    for (int i = 0; i < APT/4; i++) {
        int4 v = tp[i];
        #pragma unroll
        for (int q = 0; q < 8; q++)
            c[q] += (v.x == q) + (v.y == q) + (v.z == q) + (v.w == q);
    }
    int excl[8], wtot[8];
    #pragma unroll
    for (int e = 0; e < 8; e++) {
        int s = c[e];
        for (int off = 1; off < 64; off <<= 1) {
            int n = __shfl_up(s, off, 64);
            if (lane >= off) s += n;
        }
        excl[e] = s - c[e];
        wtot[e] = __shfl(s, 63, 64);
    }
    __shared__ int woff[4][8];
    if (lane == 0) {
        #pragma unroll
        for (int e = 0; e < 8; e++) woff[w][e] = wtot[e];
    }
    __syncthreads();
    if (tid == 0) {
        for (int e = 0; e < 8; e++) {
            int run = 0;
            for (int ww = 0; ww < 4; ww++) { int t0 = woff[ww][e]; woff[ww][e] = run; run += t0; }
            kept[e] = run < CAP ? run : CAP;
        }
    }
    __syncthreads();
    int run[8];
    #pragma unroll
    for (int e = 0; e < 8; e++) run[e] = woff[w][e] + excl[e];
    for (int i = 0; i < APT/4; i++) {
        int4 v = tp[i];
        int ev[4] = {v.x, v.y, v.z, v.w};
        #pragma unroll
        for (int u = 0; u < 4; u++) {
            int a = base + i*4 + u;
            int e = ev[u];
            int p = 0;
            #pragma unroll
            for (int q = 0; q < 8; q++) if (e == q) { p = run[q]; run[q] = p + 1; }
            pos[a] = p;
            if (p < CAP) slot_tok[(size_t)e * CAP + p] = a >> 1;
        }
    }
}

// ------------- dispatch: gather kept tokens -> bf16 [E][CAP][D] -------------
__global__ void dispatch_kernel(const float* __restrict__ x,
                                const int* __restrict__ slot_tok,
                                const int* __restrict__ kept,
                                unsigned short* __restrict__ xb) {
    int row  = blockIdx.x * 4 + (threadIdx.x >> 6);
    int lane = threadIdx.x & 63;
    int e = row / CAP;
    int p = row - e * CAP;
    if (p >= kept[e]) return;           // wave-uniform
    int t = slot_tok[row];
    const float4* src = reinterpret_cast<const float4*>(x + (size_t)t * DMODEL);
    ushort4* dst = reinterpret_cast<ushort4*>(xb + (size_t)row * DMODEL);
    #pragma unroll
    for (int i = lane; i < DMODEL/4; i += 64) {
        float4 v = src[i];
        ushort4 o;
        o.x = f2bf(v.x); o.y = f2bf(v.y); o.z = f2bf(v.z); o.w = f2bf(v.w);
        dst[i] = o;
    }
}

// ------------- transpose fp32 [e][R][C] -> bf16 [e][C][R] -------------
// 64x64 tile; float4 coalesced loads, ushort8 (16B) coalesced stores.
// LDS pad 65 (stride ≡ 1 mod 32 -> all phases 2-way max = free).
__global__ void transpose_f32_to_bf16(const float* __restrict__ in,
                                      unsigned short* __restrict__ out,
                                      int R, int C) {
    __shared__ float tile[64 * 65];
    int e = blockIdx.z;
    const float* src = in + (size_t)e * R * C;
    unsigned short* dst = out + (size_t)e * R * C;
    int c0 = blockIdx.x * 64, r0 = blockIdx.y * 64;
    int t = threadIdx.x;
    int lr4 = (t & 15) * 4;
    #pragma unroll
    for (int s = 0; s < 4; s++) {
        int r = (t >> 4) + s * 16;
        float4 v = *reinterpret_cast<const float4*>(&src[(size_t)(r0 + r) * C + c0 + lr4]);
        float* tr = &tile[r * 65 + lr4];
        tr[0] = v.x; tr[1] = v.y; tr[2] = v.z; tr[3] = v.w;
    }
    __syncthreads();
    int j = t & 7;            // 8-short chunk along original-row (output col) dim
    int ccb = t >> 3;         // 0..31
    #pragma unroll
    for (int s = 0; s < 2; s++) {
        int cc = ccb + s * 32;        // transposed row = original col
        u16x8 o;
        #pragma unroll
        for (int k = 0; k < 8; k++) o[k] = f2bf(tile[(j * 8 + k) * 65 + cc]);
        *reinterpret_cast<u16x8*>(&dst[(size_t)(c0 + cc) * R + r0 + j * 8]) = o;
    }
}

// ------------- GEMM: C[e][M][N] = A[e][M][K] * Bt[e][N][K]^T + bias -------------
// A,Bt bf16 k-contiguous; C bf16; optional exact GELU.
// Staging: global_load_lds width=16, XOR-swizzled source chunks (LDS dst is
// wave-uniform base + lane*16 -> no padding possible; swizzle instead).
template<int GELU>
__global__ __launch_bounds__(256, 2)
void gemm_bt(const unsigned short* __restrict__ A,
             const unsigned short* __restrict__ Bt,
             const float* __restrict__ bias,
             unsigned short* __restrict__ C,
             int M, int N, int K) {
    constexpr int BM = 128, BN = 128, BK = 64;
    __shared__ unsigned short As[BM * 64];   // row-major, chunk-swizzled
    __shared__ unsigned short Bs[BN * 64];
    const int e = blockIdx.z;
    const unsigned short* Ab = A  + (size_t)e * M * K + (size_t)blockIdx.y * BM * K;
    const unsigned short* Bb = Bt + (size_t)e * N * K + (size_t)blockIdx.x * BN * K;
    const float* bp = bias + (size_t)e * N;
    const int tid  = threadIdx.x;
    const int lane = tid & 63;
    const int wv   = tid >> 6;
    const int wm   = (wv >> 1) * 64;
    const int wn   = (wv & 1) * 64;
    const int lr   = lane & 15;
    const int quad = lane >> 4;
    // staging: lane -> (row-in-group, stored chunk); source chunk is XOR-swizzled
    const int srow   = lane >> 3;                 // 0..7
    const int schunk = (lane & 7) ^ srow;         // source 8-short chunk
    const int swiz   = lr & 7;                    // read-side unswizzle key

    f32x4 acc[4][4] = {};

    for (int kb = 0; kb < K; kb += BK) {
        #pragma unroll
        for (int s = 0; s < 4; s++) {
            int q = wv * 4 + s;                   // 8-row group 0..15
            int row = q * 8 + srow;
            __builtin_amdgcn_global_load_lds(
                (const __attribute__((address_space(1))) unsigned int*)(Ab + (size_t)row * K + kb + schunk * 8),
                (__attribute__((address_space(3))) unsigned int*)(As + q * 512),
                16, 0, 0);
            __builtin_amdgcn_global_load_lds(
                (const __attribute__((address_space(1))) unsigned int*)(Bb + (size_t)row * K + kb + schunk * 8),
                (__attribute__((address_space(3))) unsigned int*)(Bs + q * 512),
                16, 0, 0);
        }
        __syncthreads();
        #pragma unroll
        for (int kk = 0; kk < BK; kk += 32) {
            bf16x8 af[4], bfr[4];
            const int sc = ((kk >> 3) + quad) ^ swiz;   // stored chunk for this lane
            #pragma unroll
            for (int i = 0; i < 4; i++)
                af[i] = *reinterpret_cast<const bf16x8*>(&As[(wm + i*16 + lr) * 64 + sc * 8]);
            #pragma unroll
            for (int j = 0; j < 4; j++)
                bfr[j] = *reinterpret_cast<const bf16x8*>(&Bs[(wn + j*16 + lr) * 64 + sc * 8]);
            #pragma unroll
            for (int i = 0; i < 4; i++)
                #pragma unroll
                for (int j = 0; j < 4; j++)
                    acc[i][j] = __builtin_amdgcn_mfma_f32_16x16x32_bf16(af[i], bfr[j], acc[i][j], 0, 0, 0);
        }
        __syncthreads();
    }

    size_t cbase = (size_t)e * M * N + (size_t)blockIdx.y * BM * N + (size_t)blockIdx.x * BN;
    float bv[4];
    #pragma unroll
    for (int j = 0; j < 4; j++) bv[j] = bp[blockIdx.x * BN + wn + j * 16 + lr];
    #pragma unroll
    for (int i = 0; i < 4; i++) {
        #pragma unroll
        for (int r = 0; r < 4; r++) {
            int row = wm + i * 16 + quad * 4 + r;
            #pragma unroll
            for (int j = 0; j < 4; j++) {
                int col = wn + j * 16 + lr;
                float v = acc[i][j][r] + bv[j];
                if (GELU) v = 0.5f * v * (1.f + erff(v * 0.70710678118654752440f));
                C[cbase + (size_t)row * N + col] = f2bf(v);
            }
        }
    }
}

// ------------- combine: weighted sum of expert outputs, normalize -------------
__global__ void combine_kernel(const int* __restrict__ topi,
                               const float* __restrict__ topv,
                               const int* __restrict__ pos,
                               const unsigned short* __restrict__ out2,
                               float* __restrict__ y) {
    int t    = blockIdx.x * 4 + (threadIdx.x >> 6);
    int lane = threadIdx.x & 63;
    int e0 = topi[t*2],   e1 = topi[t*2+1];
    float g0 = topv[t*2], g1 = topv[t*2+1];
    int p0 = pos[t*2],    p1 = pos[t*2+1];
    float w0 = (p0 < CAP) ? g0 : 0.f;
    float w1 = (p1 < CAP) ? g1 : 0.f;
    float wsum = w0 + w1;
    float scale = (wsum > 0.f) ? 1.f / fmaxf(wsum, 1e-6f) : 0.f;
    int q0 = p0 < CAP ? p0 : CAP - 1;
    int q1 = p1 < CAP ? p1 : CAP - 1;
    const ushort4* o0 = reinterpret_cast<const ushort4*>(out2 + ((size_t)e0 * CAP + q0) * DMODEL);
    const ushort4* o1 = reinterpret_cast<const ushort4*>(out2 + ((size_t)e1 * CAP + q1) * DMODEL);
    float4* dst = reinterpret_cast<float4*>(y + (size_t)t * DMODEL);
    #pragma unroll
    for (int i = lane; i < DMODEL/4; i += 64) {
        ushort4 a = o0[i], b = o1[i];
        float4 r;
        r.x = (w0 * bf2f(a.x) + w1 * bf2f(b.x)) * scale;
        r.y = (w0 * bf2f(a.y) + w1 * bf2f(b.y)) * scale;
        r.z = (w0 * bf2f(a.z) + w1 * bf2f(b.z)) * scale;
        r.w = (w0 * bf2f(a.w) + w1 * bf2f(b.w)) * scale;
        dst[i] = r;
    }
}

extern "C" void kernel_launch(void* const* d_in, const int* in_sizes, int n_in,
                              void* d_out, int out_size, void* d_ws, size_t ws_size,
                              hipStream_t stream) {
    (void)in_sizes; (void)n_in; (void)out_size; (void)ws_size;
    const float* x        = (const float*)d_in[0];
    const float* w_router = (const float*)d_in[1];
    const float* b_router = (const float*)d_in[2];
    const float* w1       = (const float*)d_in[3];
    const float* b1       = (const float*)d_in[4];
    const float* w2       = (const float*)d_in[5];
    const float* b2       = (const float*)d_in[6];
    float* y = (float*)d_out;

    char* ws = (char*)d_ws;
    size_t off = 0;
    auto alloc = [&](size_t n) { char* p = ws + off; off = (off + n + 255) & ~(size_t)255; return p; };
    int*   topi     = (int*)  alloc((size_t)NASSIGN * 4);
    float* topv     = (float*)alloc((size_t)NASSIGN * 4);
    int*   pos      = (int*)  alloc((size_t)NASSIGN * 4);
    int*   slot_tok = (int*)  alloc((size_t)NEXP * CAP * 4);
    int*   kept     = (int*)  alloc(8 * 4);
    unsigned short* w1t = (unsigned short*)alloc((size_t)NEXP * DMODEL * FFF * 2);
    unsigned short* w2t = (unsigned short*)alloc((size_t)NEXP * DMODEL * FFF * 2);
    unsigned short* xb  = (unsigned short*)alloc((size_t)NEXP * CAP * DMODEL * 2);
    unsigned short* h   = (unsigned short*)alloc((size_t)NEXP * CAP * FFF * 2);
    unsigned short* out2 = w1t;  // alias: w1t is dead after GEMM1

    router_kernel<<<NTOK/4, 256, 0, stream>>>(x, w_router, b_router, topi, topv);
    scan_kernel<<<1, 256, 0, stream>>>(topi, pos, slot_tok, kept);
    dispatch_kernel<<<NEXP*CAP/4, 256, 0, stream>>>(x, slot_tok, kept, xb);
    transpose_f32_to_bf16<<<dim3(FFF/64, DMODEL/64, NEXP), 256, 0, stream>>>(w1, w1t, DMODEL, FFF);
    transpose_f32_to_bf16<<<dim3(DMODEL/64, FFF/64, NEXP), 256, 0, stream>>>(w2, w2t, FFF, DMODEL);
    gemm_bt<1><<<dim3(FFF/128, CAP/128, NEXP), 256, 0, stream>>>(xb, w1t, b1, h, CAP, FFF, DMODEL);
    gemm_bt<0><<<dim3(DMODEL/128, CAP/128, NEXP), 256, 0, stream>>>(h, w2t, b2, out2, CAP, DMODEL, FFF);
    combine_kernel<<<NTOK/4, 256, 0, stream>>>(topi, topv, pos, out2, y);
}

// Round 3
// 913.098 us; speedup vs baseline: 1.0949x; 1.0016x over previous
//
#include <hip/hip_runtime.h>

// ---- problem constants (match reference) ----
#define NTOK   16384      // B*T
#define DMODEL 1024
#define FFF    4096
#define NEXP   8
#define CAP    2560       // int(1.25 * NTOK / NEXP)
#define NASSIGN (NTOK*2)  // top-2

typedef __bf16 bf16x8 __attribute__((ext_vector_type(8)));
typedef float  f32x4  __attribute__((ext_vector_type(4)));
typedef unsigned short u16x8 __attribute__((ext_vector_type(8)));

__device__ __forceinline__ unsigned short f2bf(float f) {
    unsigned int u = __float_as_uint(f);
    u = u + 0x7FFFu + ((u >> 16) & 1u);   // RNE
    return (unsigned short)(u >> 16);
}
__device__ __forceinline__ float bf2f(unsigned short s) {
    return __uint_as_float(((unsigned int)s) << 16);
}

// ======== fused prologue: router (blocks 0..4095) + w1/w2 transpose ========
// router: one wave per token, fp32 logits -> softmax -> top2
__device__ void router_body(int rb, const float* __restrict__ x,
                            const float* __restrict__ wr,
                            const float* __restrict__ br,
                            int* __restrict__ topi,
                            float* __restrict__ topv) {
    int t    = rb * 4 + (threadIdx.x >> 6);
    int lane = threadIdx.x & 63;
    const float4* xr4 = reinterpret_cast<const float4*>(x + (size_t)t * DMODEL);
    float a[8] = {0.f,0.f,0.f,0.f,0.f,0.f,0.f,0.f};
    #pragma unroll
    for (int i = lane; i < DMODEL/4; i += 64) {
        float4 xv = xr4[i];
        const float* w = wr + i * 32;
        #pragma unroll
        for (int e = 0; e < 8; e++) a[e] = fmaf(xv.x, w[e],      a[e]);
        #pragma unroll
        for (int e = 0; e < 8; e++) a[e] = fmaf(xv.y, w[8 + e],  a[e]);
        #pragma unroll
        for (int e = 0; e < 8; e++) a[e] = fmaf(xv.z, w[16 + e], a[e]);
        #pragma unroll
        for (int e = 0; e < 8; e++) a[e] = fmaf(xv.w, w[24 + e], a[e]);
    }
    #pragma unroll
    for (int off = 32; off > 0; off >>= 1) {
        #pragma unroll
        for (int e = 0; e < 8; e++) a[e] += __shfl_xor(a[e], off, 64);
    }
    if (lane == 0) {
        float l[8], g[8];
        float mx = -1e30f;
        #pragma unroll
        for (int e = 0; e < 8; e++) { l[e] = a[e] + br[e]; mx = fmaxf(mx, l[e]); }
        float s = 0.f;
        #pragma unroll
        for (int e = 0; e < 8; e++) { g[e] = expf(l[e] - mx); s += g[e]; }
        float inv = 1.f / s;
        #pragma unroll
        for (int e = 0; e < 8; e++) g[e] *= inv;
        float v1 = -1.f, v2 = -1.f; int i1 = 0, i2 = 0;
        #pragma unroll
        for (int e = 0; e < 8; e++) {
            float v = g[e];
            if (v > v1)      { v2 = v1; i2 = i1; v1 = v; i1 = e; }
            else if (v > v2) { v2 = v; i2 = e; }
        }
        topi[t*2]   = i1; topi[t*2+1] = i2;
        topv[t*2]   = v1; topv[t*2+1] = v2;
    }
}

// transpose fp32 [R][C] tile (r0,c0) -> bf16 [C][R]; 64x64, pad 65 (2-way max)
__device__ void transpose_body(const float* __restrict__ src,
                               unsigned short* __restrict__ dst,
                               int R, int C, int r0, int c0) {
    __shared__ float tile[64 * 65];
    int t = threadIdx.x;
    int lr4 = (t & 15) * 4;
    #pragma unroll
    for (int s = 0; s < 4; s++) {
        int r = (t >> 4) + s * 16;
        float4 v = *reinterpret_cast<const float4*>(&src[(size_t)(r0 + r) * C + c0 + lr4]);
        float* tr = &tile[r * 65 + lr4];
        tr[0] = v.x; tr[1] = v.y; tr[2] = v.z; tr[3] = v.w;
    }
    __syncthreads();
    int j = t & 7;
    int ccb = t >> 3;
    #pragma unroll
    for (int s = 0; s < 2; s++) {
        int cc = ccb + s * 32;
        u16x8 o;
        #pragma unroll
        for (int k = 0; k < 8; k++) o[k] = f2bf(tile[(j * 8 + k) * 65 + cc]);
        *reinterpret_cast<u16x8*>(&dst[(size_t)(c0 + cc) * R + r0 + j * 8]) = o;
    }
}

__global__ void prologue_kernel(const float* __restrict__ x,
                                const float* __restrict__ wr,
                                const float* __restrict__ br,
                                const float* __restrict__ w1,
                                const float* __restrict__ w2,
                                int* __restrict__ topi,
                                float* __restrict__ topv,
                                unsigned short* __restrict__ w1t,
                                unsigned short* __restrict__ w2t) {
    int id = blockIdx.x;
    if (id < NTOK/4) {
        router_body(id, x, wr, br, topi, topv);
    } else if (id < NTOK/4 + 8192) {
        // w1 [e][D][F] -> w1t [e][F][D]; 1024 blocks/expert (64 x-chunks, 16 y)
        int q = id - NTOK/4;
        int e = q >> 10, t = q & 1023;
        int bx = t & 63, by = t >> 6;
        transpose_body(w1 + (size_t)e * DMODEL * FFF,
                       w1t + (size_t)e * DMODEL * FFF,
                       DMODEL, FFF, by * 64, bx * 64);
    } else {
        // w2 [e][F][D] -> w2t [e][D][F]; 1024 blocks/expert (16 x-chunks, 64 y)
        int q = id - NTOK/4 - 8192;
        int e = q >> 10, t = q & 1023;
        int bx = t & 15, by = t >> 4;
        transpose_body(w2 + (size_t)e * DMODEL * FFF,
                       w2t + (size_t)e * DMODEL * FFF,
                       FFF, DMODEL, by * 64, bx * 64);
    }
}

// ------- scan: arrival-order positions per expert (single block) -------
__global__ void scan_kernel(const int* __restrict__ topi,
                            int* __restrict__ pos,
                            int* __restrict__ slot_tok,
                            int* __restrict__ kept) {
    const int APT = NASSIGN / 256;
    int tid = threadIdx.x, lane = tid & 63, w = tid >> 6;
    int base = tid * APT;
    const int4* tp = reinterpret_cast<const int4*>(topi + base);
    int c[8] = {0,0,0,0,0,0,0,0};
    for (int i = 0; i < APT/4; i++) {
        int4 v = tp[i];
        #pragma unroll
        for (int q = 0; q < 8; q++)
            c[q] += (v.x == q) + (v.y == q) + (v.z == q) + (v.w == q);
    }
    int excl[8], wtot[8];
    #pragma unroll
    for (int e = 0; e < 8; e++) {
        int s = c[e];
        for (int off = 1; off < 64; off <<= 1) {
            int n = __shfl_up(s, off, 64);
            if (lane >= off) s += n;
        }
        excl[e] = s - c[e];
        wtot[e] = __shfl(s, 63, 64);
    }
    __shared__ int woff[4][8];
    if (lane == 0) {
        #pragma unroll
        for (int e = 0; e < 8; e++) woff[w][e] = wtot[e];
    }
    __syncthreads();
    if (tid == 0) {
        for (int e = 0; e < 8; e++) {
            int run = 0;
            for (int ww = 0; ww < 4; ww++) { int t0 = woff[ww][e]; woff[ww][e] = run; run += t0; }
            kept[e] = run < CAP ? run : CAP;
        }
    }
    __syncthreads();
    int run[8];
    #pragma unroll
    for (int e = 0; e < 8; e++) run[e] = woff[w][e] + excl[e];
    for (int i = 0; i < APT/4; i++) {
        int4 v = tp[i];
        int ev[4] = {v.x, v.y, v.z, v.w};
        #pragma unroll
        for (int u = 0; u < 4; u++) {
            int a = base + i*4 + u;
            int e = ev[u];
            int p = 0;
            #pragma unroll
            for (int q = 0; q < 8; q++) if (e == q) { p = run[q]; run[q] = p + 1; }
            pos[a] = p;
            if (p < CAP) slot_tok[(size_t)e * CAP + p] = a >> 1;
        }
    }
}

// ------------- dispatch: gather kept tokens -> bf16 [E][CAP][D] -------------
__global__ void dispatch_kernel(const float* __restrict__ x,
                                const int* __restrict__ slot_tok,
                                const int* __restrict__ kept,
                                unsigned short* __restrict__ xb) {
    int row  = blockIdx.x * 4 + (threadIdx.x >> 6);
    int lane = threadIdx.x & 63;
    int e = row / CAP;
    int p = row - e * CAP;
    if (p >= kept[e]) return;           // wave-uniform
    int t = slot_tok[row];
    const float4* src = reinterpret_cast<const float4*>(x + (size_t)t * DMODEL);
    ushort4* dst = reinterpret_cast<ushort4*>(xb + (size_t)row * DMODEL);
    #pragma unroll
    for (int i = lane; i < DMODEL/4; i += 64) {
        float4 v = src[i];
        ushort4 o;
        o.x = f2bf(v.x); o.y = f2bf(v.y); o.z = f2bf(v.z); o.w = f2bf(v.w);
        dst[i] = o;
    }
}

// ------------- GEMM: C[e][M][N] = A[e][M][K] * Bt[e][N][K]^T + bias -------------
// global_load_lds width=16, XOR chunk swizzle. Block order: per expert, N in
// chunks of 8 tiles with N fastest -> each XCD pins one B-tile in its L2 while
// A streams (L3-resident). grid = dim3(gx*gy, 1, NEXP).
template<int GELU>
__global__ __launch_bounds__(256, 2)
void gemm_bt(const unsigned short* __restrict__ A,
             const unsigned short* __restrict__ Bt,
             const float* __restrict__ bias,
             unsigned short* __restrict__ C,
             int M, int N, int K) {
    constexpr int BM = 128, BN = 128, BK = 64;
    __shared__ unsigned short As[BM * 64];
    __shared__ unsigned short Bs[BN * 64];
    const int e = blockIdx.z;
    const int gx = N / BN, gy = M / BM;
    const int nc = gx < 8 ? gx : 8;          // n-chunk width
    int id = blockIdx.x;
    const int per_chunk = nc * gy;
    const int chunk = id / per_chunk;
    const int r = id - chunk * per_chunk;
    const int bn = chunk * nc + (r % nc);
    const int bm = r / nc;

    const unsigned short* Ab = A  + (size_t)e * M * K + (size_t)bm * BM * K;
    const unsigned short* Bb = Bt + (size_t)e * N * K + (size_t)bn * BN * K;
    const float* bp = bias + (size_t)e * N;
    const int tid  = threadIdx.x;
    const int lane = tid & 63;
    const int wv   = tid >> 6;
    const int wm   = (wv >> 1) * 64;
    const int wn   = (wv & 1) * 64;
    const int lr   = lane & 15;
    const int quad = lane >> 4;
    const int srow   = lane >> 3;
    const int schunk = (lane & 7) ^ srow;
    const int swiz   = lr & 7;

    f32x4 acc[4][4] = {};

    for (int kb = 0; kb < K; kb += BK) {
        #pragma unroll
        for (int s = 0; s < 4; s++) {
            int q = wv * 4 + s;
            int row = q * 8 + srow;
            __builtin_amdgcn_global_load_lds(
                (const __attribute__((address_space(1))) unsigned int*)(Ab + (size_t)row * K + kb + schunk * 8),
                (__attribute__((address_space(3))) unsigned int*)(As + q * 512),
                16, 0, 0);
            __builtin_amdgcn_global_load_lds(
                (const __attribute__((address_space(1))) unsigned int*)(Bb + (size_t)row * K + kb + schunk * 8),
                (__attribute__((address_space(3))) unsigned int*)(Bs + q * 512),
                16, 0, 0);
        }
        __syncthreads();
        #pragma unroll
        for (int kk = 0; kk < BK; kk += 32) {
            bf16x8 af[4], bfr[4];
            const int sc = ((kk >> 3) + quad) ^ swiz;
            #pragma unroll
            for (int i = 0; i < 4; i++)
                af[i] = *reinterpret_cast<const bf16x8*>(&As[(wm + i*16 + lr) * 64 + sc * 8]);
            #pragma unroll
            for (int j = 0; j < 4; j++)
                bfr[j] = *reinterpret_cast<const bf16x8*>(&Bs[(wn + j*16 + lr) * 64 + sc * 8]);
            #pragma unroll
            for (int i = 0; i < 4; i++)
                #pragma unroll
                for (int j = 0; j < 4; j++)
                    acc[i][j] = __builtin_amdgcn_mfma_f32_16x16x32_bf16(af[i], bfr[j], acc[i][j], 0, 0, 0);
        }
        __syncthreads();
    }

    size_t cbase = (size_t)e * M * N + (size_t)bm * BM * N + (size_t)bn * BN;
    float bv[4];
    #pragma unroll
    for (int j = 0; j < 4; j++) bv[j] = bp[bn * BN + wn + j * 16 + lr];
    #pragma unroll
    for (int i = 0; i < 4; i++) {
        #pragma unroll
        for (int rr = 0; rr < 4; rr++) {
            int row = wm + i * 16 + quad * 4 + rr;
            #pragma unroll
            for (int j = 0; j < 4; j++) {
                int col = wn + j * 16 + lr;
                float v = acc[i][j][rr] + bv[j];
                if (GELU) v = 0.5f * v * (1.f + erff(v * 0.70710678118654752440f));
                C[cbase + (size_t)row * N + col] = f2bf(v);
            }
        }
    }
}

// ------------- combine: weighted sum of expert outputs, normalize -------------
__global__ void combine_kernel(const int* __restrict__ topi,
                               const float* __restrict__ topv,
                               const int* __restrict__ pos,
                               const unsigned short* __restrict__ out2,
                               float* __restrict__ y) {
    int t    = blockIdx.x * 4 + (threadIdx.x >> 6);
    int lane = threadIdx.x & 63;
    int e0 = topi[t*2],   e1 = topi[t*2+1];
    float g0 = topv[t*2], g1 = topv[t*2+1];
    int p0 = pos[t*2],    p1 = pos[t*2+1];
    float w0 = (p0 < CAP) ? g0 : 0.f;
    float w1 = (p1 < CAP) ? g1 : 0.f;
    float wsum = w0 + w1;
    float scale = (wsum > 0.f) ? 1.f / fmaxf(wsum, 1e-6f) : 0.f;
    int q0 = p0 < CAP ? p0 : CAP - 1;
    int q1 = p1 < CAP ? p1 : CAP - 1;
    const ushort4* o0 = reinterpret_cast<const ushort4*>(out2 + ((size_t)e0 * CAP + q0) * DMODEL);
    const ushort4* o1 = reinterpret_cast<const ushort4*>(out2 + ((size_t)e1 * CAP + q1) * DMODEL);
    float4* dst = reinterpret_cast<float4*>(y + (size_t)t * DMODEL);
    #pragma unroll
    for (int i = lane; i < DMODEL/4; i += 64) {
        ushort4 a = o0[i], b = o1[i];
        float4 r;
        r.x = (w0 * bf2f(a.x) + w1 * bf2f(b.x)) * scale;
        r.y = (w0 * bf2f(a.y) + w1 * bf2f(b.y)) * scale;
        r.z = (w0 * bf2f(a.z) + w1 * bf2f(b.z)) * scale;
        r.w = (w0 * bf2f(a.w) + w1 * bf2f(b.w)) * scale;
        dst[i] = r;
    }
}

extern "C" void kernel_launch(void* const* d_in, const int* in_sizes, int n_in,
                              void* d_out, int out_size, void* d_ws, size_t ws_size,
                              hipStream_t stream) {
    (void)in_sizes; (void)n_in; (void)out_size; (void)ws_size;
    const float* x        = (const float*)d_in[0];
    const float* w_router = (const float*)d_in[1];
    const float* b_router = (const float*)d_in[2];
    const float* w1       = (const float*)d_in[3];
    const float* b1       = (const float*)d_in[4];
    const float* w2       = (const float*)d_in[5];
    const float* b2       = (const float*)d_in[6];
    float* y = (float*)d_out;

    char* ws = (char*)d_ws;
    size_t off = 0;
    auto alloc = [&](size_t n) { char* p = ws + off; off = (off + n + 255) & ~(size_t)255; return p; };
    int*   topi     = (int*)  alloc((size_t)NASSIGN * 4);
    float* topv     = (float*)alloc((size_t)NASSIGN * 4);
    int*   pos      = (int*)  alloc((size_t)NASSIGN * 4);
    int*   slot_tok = (int*)  alloc((size_t)NEXP * CAP * 4);
    int*   kept     = (int*)  alloc(8 * 4);
    unsigned short* w1t = (unsigned short*)alloc((size_t)NEXP * DMODEL * FFF * 2);
    unsigned short* w2t = (unsigned short*)alloc((size_t)NEXP * DMODEL * FFF * 2);
    unsigned short* xb  = (unsigned short*)alloc((size_t)NEXP * CAP * DMODEL * 2);
    unsigned short* h   = (unsigned short*)alloc((size_t)NEXP * CAP * FFF * 2);
    unsigned short* out2 = w1t;  // alias: w1t is dead after GEMM1

    prologue_kernel<<<NTOK/4 + 16384, 256, 0, stream>>>(
        x, w_router, b_router, w1, w2, topi, topv, w1t, w2t);
    scan_kernel<<<1, 256, 0, stream>>>(topi, pos, slot_tok, kept);
    dispatch_kernel<<<NEXP*CAP/4, 256, 0, stream>>>(x, slot_tok, kept, xb);
    gemm_bt<1><<<dim3((FFF/128)*(CAP/128), 1, NEXP), 256, 0, stream>>>(xb, w1t, b1, h, CAP, FFF, DMODEL);
    gemm_bt<0><<<dim3((DMODEL/128)*(CAP/128), 1, NEXP), 256, 0, stream>>>(h, w2t, b2, out2, CAP, DMODEL, FFF);
    combine_kernel<<<NTOK/4, 256, 0, stream>>>(topi, topv, pos, out2, y);
}